// Round 17
// baseline (451.828 us; speedup 1.0000x reference)
//
#include <hip/hip_runtime.h>
#include <math.h>

#define DD 128
#define HW 512
#define MG 514

// Verified reference stack (r10/r11/r14): G1 predux-tree colmajor conv,
// contract-off mul/add mag, fd-hybrid classifier.
// r17: register-rolling shuffle-based k_nms (no LDS, no index divisions).

// ---- fdlibm/glibc float atan (bit-exact port) ----
static __device__ float fd_atanf(float x) {
    #pragma clang fp contract(off)
    const unsigned hx = __float_as_uint(x);
    const unsigned ix = hx & 0x7fffffffu;
    const double A0 = 0.46364760900080611621425623146121440203;
    const double A1 = 0.78539816339744830961566084581987572105;
    const double A2 = 0.98279372324732906798571061101466601449;
    const double A3 = 1.57079632679489661923132169163975144210;
    const float aT0 =  3.3333328366e-01f;
    const float aT1 = -1.9999158382e-01f;
    const float aT2 =  1.4253635705e-01f;
    const float aT3 = -1.0648017377e-01f;
    const float aT4 =  6.1687607318e-02f;
    float z, w, s1, s2;
    int id;
    double a;
    if (ix >= 0x4c800000u) {
        a = A3;
        float hi = (float)a; if ((double)hi > a) hi = __uint_as_float(__float_as_uint(hi) - 1u);
        float lo = (float)(a - (double)hi);
        float r = hi + lo;
        return (hx >> 31) ? -r : r;
    }
    if (ix < 0x3ee00000u) {
        if (ix < 0x39800000u) return x;
        id = -1;
    } else {
        x = fabsf(x);
        if (ix < 0x3f980000u) {
            if (ix < 0x3f300000u) { id = 0; x = (2.0f * x - 1.0f) / (2.0f + x); }
            else                  { id = 1; x = (x - 1.0f) / (x + 1.0f); }
        } else {
            if (ix < 0x401c0000u) { id = 2; x = (x - 1.5f) / (1.0f + 1.5f * x); }
            else                  { id = 3; x = -1.0f / x; }
        }
    }
    z = x * x;
    w = z * z;
    s1 = z * (aT0 + w * (aT2 + w * aT4));
    s2 = w * (aT1 + w * aT3);
    if (id < 0) return x - x * (s1 + s2);
    a = (id == 0) ? A0 : (id == 1) ? A1 : (id == 2) ? A2 : A3;
    float hi = (float)a; if ((double)hi > a) hi = __uint_as_float(__float_as_uint(hi) - 1u);
    float lo = (float)(a - (double)hi);
    z = hi - ((x * (s1 + s2) - lo) - x);
    return (hx >> 31) ? -z : z;
}

static __device__ int cls_fd(float y, float x) {
    #pragma clang fp contract(off)
    const unsigned hx = __float_as_uint(x), hy = __float_as_uint(y);
    const unsigned ix = hx & 0x7fffffffu, iy = hy & 0x7fffffffu;
    unsigned m = ((hy >> 31) & 1u) | ((hx >> 30) & 2u);
    const double PI_D = 3.14159265358979323846264338327950288420;
    const float pi_f  = (float)PI_D;
    const float pi_lo = (float)(PI_D - (double)pi_f);
    const float pi4_f = (float)(PI_D / 4.0);
    const float pi2_f = (float)(PI_D / 2.0);
    float v;
    if (iy == 0) {
        v = (m == 0 || m == 1) ? y : (m == 2 ? pi_f : -pi_f);
    } else if (ix == 0) {
        v = (m & 1u) ? -pi2_f : pi2_f;
    } else if (ix + (26u << 23) < iy) {
        v = (m & 1u) ? -pi2_f : pi2_f;
    } else {
        float z;
        if ((m & 2u) && iy + (26u << 23) < ix) z = 0.0f;
        else z = fd_atanf(fabsf(y / x));
        switch (m) {
            case 0:  v = z; break;
            case 1:  v = -z; break;
            case 2:  v = pi_f - (z - pi_lo); break;
            default: v = (z - pi_lo) - pi_f; break;
        }
    }
    float t = v / pi4_f;
    int n = (int)rintf(t);
    return n & 3;
}

static __device__ __forceinline__ int classify(float gx, float gy) {
    #pragma clang fp contract(off)
    float ax = fabsf(gx), ay = fabsf(gy);
    const float T = 0.41421356237309504880f;   // tan(pi/8)
    float r1 = ay - ax * T;
    float r2 = ax - ay * T;
    float eps = 1e-4f * (ax + ay);
    if (fabsf(r1) > eps && fabsf(r2) > eps) {
        if (r1 < 0.0f) return 0;
        if (r2 < 0.0f) return 2;
        return ((__float_as_uint(gx) ^ __float_as_uint(gy)) >> 31) ? 3 : 1;
    }
    return cls_fd(gy, gx);
}

// ---------- k1: register-rolling NMS (one wave = 64 cols, 16-row strip) ----------
__global__ __launch_bounds__(256) void k_nms(const float* __restrict__ x,
                                             float* __restrict__ nms,
                                             unsigned int* __restrict__ smax) {
    const int lane = threadIdx.x;               // 0..63 = column within window
    const int ty   = threadIdx.y;               // 0..3  = wave id
    const int d    = blockIdx.z;
    const int J0   = blockIdx.x * 60;           // output col origin
    const int r0   = blockIdx.y * 64 + ty * 16; // output row origin for this wave
    if (r0 >= MG) return;                       // fully-masked wave

    // lane's x-grid column (wrapped), x source column, validity
    int ucol = J0 - 2 + lane;                   // unwrapped grid col (-2 .. 541)
    int cxg  = ucol + ((ucol < 0) ? MG : 0);  cxg -= (cxg >= MG) ? MG : 0;
    const bool colOK   = (unsigned)(cxg - 1) < (unsigned)HW;
    const int  xcol    = colOK ? (cxg - 1) : 0;
    const bool outLane = (lane >= 2) && (lane <= 61) && (ucol < MG);
    const float* xd = x + (size_t)d * HW * HW;
    float* nd = nms + (size_t)d * MG * MG;

    float xm[3], xl[3], xr[3];      // x rows (center/left/right), rotating
    float mg[3], ml[3], mr[3];      // mag rows
    int   cl[3];
    float tmax = 0.0f;

    #pragma unroll
    for (int k = 0; k < 20; ++k) {
        // ---- load x grid row r0-2+k (wrapped, zero ring) ----
        int R = r0 - 2 + k;
        R += (R < 0) ? MG : 0;  R -= (R >= MG) ? MG : 0;
        float xv = 0.0f;
        if ((unsigned)(R - 1) < (unsigned)HW) {         // wave-uniform branch
            xv = xd[(size_t)(R - 1) * HW + xcol];
            xv = colOK ? xv : 0.0f;
        }
        xm[k % 3] = xv;
        xl[k % 3] = __shfl_up(xv, 1);
        xr[k % 3] = __shfl_down(xv, 1);

        // ---- mag/cls for mag row j = k-2 (grid row r0-1+j) ----
        if (k >= 2) {
            const int j  = k - 2;
            const int s0 = j % 3, s1 = (j + 1) % 3, s2 = (j + 2) % 3;
            float gx, gy;
            {
                #pragma clang fp contract(off)
                float x00 = xl[s0], x01 = xm[s0], x02 = xr[s0];
                float x10 = xl[s1],               x12 = xr[s1];
                float x20 = xl[s2], x21 = xm[s2], x22 = xr[s2];
                { float A = -x00; float B = x02 + (-x20); float C = 2.0f*x12; float D = -2.0f*x10;
                  float E = A + B; float F = C + D; gx = (E + F) + x22; }
                { float A = -x00; float B = (-x02) + x20; float C = -2.0f*x01; float D = 2.0f*x21;
                  float E = A + B; float F = C + D; gy = (E + F) + x22; }
            }
            float m;
            {
                #pragma clang fp contract(off)
                float p = gx * gx;
                float q = gy * gy;
                m = sqrtf(p + q);
            }
            mg[j % 3] = m;
            ml[j % 3] = __shfl_up(m, 1);
            mr[j % 3] = __shfl_down(m, 1);
            cl[j % 3] = classify(gx, gy);
        }

        // ---- NMS for output row t = k-4 (grid row r0+t, center mag row t+1) ----
        if (k >= 4) {
            const int t  = k - 4;
            const int sA = t % 3, sB = (t + 1) % 3, sC = (t + 2) % 3;
            float m = mg[sB];
            int   c = cl[sB];
            float a = (c == 0) ? ml[sB] : (c == 1) ? ml[sA] : (c == 2) ? mg[sA] : mr[sA];
            float b = (c == 0) ? mr[sB] : (c == 1) ? mr[sC] : (c == 2) ? mg[sC] : ml[sC];
            float v = (m >= a && m >= b) ? m : 0.0f;
            int row = r0 + t;
            if (row < MG && outLane) {
                nd[(size_t)row * MG + cxg] = v;
                tmax = fmaxf(tmax, v);
            }
        }
    }

    // wave-level max -> one atomic per wave
    for (int off = 32; off > 0; off >>= 1)
        tmax = fmaxf(tmax, __shfl_down(tmax, off, 64));
    if (lane == 0)
        atomicMax(smax + d, __float_as_uint(tmax));   // nonneg: uint order-preserving
}

// ---------- k2: thresholds + 3x3 strong-pool hysteresis + crop ----------
__global__ __launch_bounds__(256) void k_edges(const float* __restrict__ nms,
                                               const unsigned int* __restrict__ smax,
                                               float* __restrict__ out) {
    __shared__ float ns[18][67];
    const int d   = blockIdx.z;
    const int ys  = blockIdx.y * 16;
    const int xs0 = blockIdx.x * 64;
    const float* nd = nms + (size_t)d * MG * MG;
    const int t = threadIdx.y * 64 + threadIdx.x;

    for (int idx = t; idx < 18 * 66; idx += 256) {
        int r = idx / 66, c = idx - r * 66;
        ns[r][c] = nd[(size_t)(ys + r) * MG + (xs0 + c)];
    }
    __syncthreads();

    const float high = __uint_as_float(smax[d]) * 0.05f;
    const float low  = high * 0.01f;

    #pragma unroll
    for (int qq = 0; qq < 4; ++qq) {
        int ry = threadIdx.y + 4 * qq;
        int y  = ys + ry, xo = xs0 + threadIdx.x;
        int r  = ry + 1,  c  = threadIdx.x + 1;
        float m = ns[r][c];
        float e;
        if (m >= high) {
            e = 1.0f;
        } else if (m >= low) {
            bool pooled =
                ns[r-1][c-1] >= high || ns[r-1][c] >= high || ns[r-1][c+1] >= high ||
                ns[r][c-1]   >= high ||                       ns[r][c+1]   >= high ||
                ns[r+1][c-1] >= high || ns[r+1][c] >= high || ns[r+1][c+1] >= high;
            e = pooled ? 1.0f : 0.0f;
        } else {
            e = 0.0f;
        }
        out[((size_t)d * HW + y) * HW + xo] = e;
    }
}

extern "C" void kernel_launch(void* const* d_in, const int* in_sizes, int n_in,
                              void* d_out, int out_size, void* d_ws, size_t ws_size,
                              hipStream_t stream) {
    const float* x = (const float*)d_in[0];
    float* out = (float*)d_out;
    float* nms = (float*)d_ws;                                   // 514*514*128*4 = 135.26 MB
    unsigned int* smax = (unsigned int*)((char*)d_ws + (size_t)DD * MG * MG * sizeof(float));

    hipMemsetAsync(smax, 0, DD * sizeof(unsigned int), stream);

    dim3 blk(64, 4, 1);
    k_nms  <<<dim3(9, 9, DD), blk, 0, stream>>>(x, nms, smax);   // 60-col x 64-row tiles
    k_edges<<<dim3(8, 32, DD), blk, 0, stream>>>(nms, smax, out);
}

// Round 18
// 391.960 us; speedup vs baseline: 1.1527x; 1.1527x over previous
//
#include <hip/hip_runtime.h>
#include <math.h>

#define DD 128
#define HW 512
#define MG 514

// Verified reference stack (r10/r11/r14): G1 predux-tree colmajor conv,
// contract-off mul/add mag, fd-hybrid classifier.
// r18: r16 structure (aligned 64-wide tiles) with division-free static
// thread->element maps; bit-identical arithmetic.

// ---- fdlibm/glibc float atan (bit-exact port) ----
static __device__ float fd_atanf(float x) {
    #pragma clang fp contract(off)
    const unsigned hx = __float_as_uint(x);
    const unsigned ix = hx & 0x7fffffffu;
    const double A0 = 0.46364760900080611621425623146121440203;
    const double A1 = 0.78539816339744830961566084581987572105;
    const double A2 = 0.98279372324732906798571061101466601449;
    const double A3 = 1.57079632679489661923132169163975144210;
    const float aT0 =  3.3333328366e-01f;
    const float aT1 = -1.9999158382e-01f;
    const float aT2 =  1.4253635705e-01f;
    const float aT3 = -1.0648017377e-01f;
    const float aT4 =  6.1687607318e-02f;
    float z, w, s1, s2;
    int id;
    double a;
    if (ix >= 0x4c800000u) {
        a = A3;
        float hi = (float)a; if ((double)hi > a) hi = __uint_as_float(__float_as_uint(hi) - 1u);
        float lo = (float)(a - (double)hi);
        float r = hi + lo;
        return (hx >> 31) ? -r : r;
    }
    if (ix < 0x3ee00000u) {
        if (ix < 0x39800000u) return x;
        id = -1;
    } else {
        x = fabsf(x);
        if (ix < 0x3f980000u) {
            if (ix < 0x3f300000u) { id = 0; x = (2.0f * x - 1.0f) / (2.0f + x); }
            else                  { id = 1; x = (x - 1.0f) / (x + 1.0f); }
        } else {
            if (ix < 0x401c0000u) { id = 2; x = (x - 1.5f) / (1.0f + 1.5f * x); }
            else                  { id = 3; x = -1.0f / x; }
        }
    }
    z = x * x;
    w = z * z;
    s1 = z * (aT0 + w * (aT2 + w * aT4));
    s2 = w * (aT1 + w * aT3);
    if (id < 0) return x - x * (s1 + s2);
    a = (id == 0) ? A0 : (id == 1) ? A1 : (id == 2) ? A2 : A3;
    float hi = (float)a; if ((double)hi > a) hi = __uint_as_float(__float_as_uint(hi) - 1u);
    float lo = (float)(a - (double)hi);
    z = hi - ((x * (s1 + s2) - lo) - x);
    return (hx >> 31) ? -z : z;
}

static __device__ int cls_fd(float y, float x) {
    #pragma clang fp contract(off)
    const unsigned hx = __float_as_uint(x), hy = __float_as_uint(y);
    const unsigned ix = hx & 0x7fffffffu, iy = hy & 0x7fffffffu;
    unsigned m = ((hy >> 31) & 1u) | ((hx >> 30) & 2u);
    const double PI_D = 3.14159265358979323846264338327950288420;
    const float pi_f  = (float)PI_D;
    const float pi_lo = (float)(PI_D - (double)pi_f);
    const float pi4_f = (float)(PI_D / 4.0);
    const float pi2_f = (float)(PI_D / 2.0);
    float v;
    if (iy == 0) {
        v = (m == 0 || m == 1) ? y : (m == 2 ? pi_f : -pi_f);
    } else if (ix == 0) {
        v = (m & 1u) ? -pi2_f : pi2_f;
    } else if (ix + (26u << 23) < iy) {
        v = (m & 1u) ? -pi2_f : pi2_f;
    } else {
        float z;
        if ((m & 2u) && iy + (26u << 23) < ix) z = 0.0f;
        else z = fd_atanf(fabsf(y / x));
        switch (m) {
            case 0:  v = z; break;
            case 1:  v = -z; break;
            case 2:  v = pi_f - (z - pi_lo); break;
            default: v = (z - pi_lo) - pi_f; break;
        }
    }
    float t = v / pi4_f;
    int n = (int)rintf(t);
    return n & 3;
}

static __device__ __forceinline__ int classify(float gx, float gy) {
    #pragma clang fp contract(off)
    float ax = fabsf(gx), ay = fabsf(gy);
    const float T = 0.41421356237309504880f;   // tan(pi/8)
    float r1 = ay - ax * T;
    float r2 = ax - ay * T;
    float eps = 1e-4f * (ax + ay);
    if (fabsf(r1) > eps && fabsf(r2) > eps) {
        if (r1 < 0.0f) return 0;
        if (r2 < 0.0f) return 2;
        return ((__float_as_uint(gx) ^ __float_as_uint(gy)) >> 31) ? 3 : 1;
    }
    return cls_fd(gy, gx);
}

// ---------- k1: stage x -> mag/cls -> NMS -> nms(ws) + per-slice max ----------
__global__ __launch_bounds__(256) void k_nms(const float* __restrict__ x,
                                             float* __restrict__ nms,
                                             unsigned int* __restrict__ smax) {
    __shared__ float         xs[20][69];
    __shared__ float         mag_s[18][67];
    __shared__ unsigned char cls_s[18][67];
    const int tx = threadIdx.x, ty = threadIdx.y;
    const int d  = blockIdx.z;
    const int i0 = blockIdx.y * 16;
    const int j0 = blockIdx.x * 64;
    const float* xd = x + (size_t)d * HW * HW;

    // ---- stage x: rows i0-2..i0+17, cols j0-2..j0+65 (wrap + zero ring) ----
    // per-thread column state, computed once
    int gc1 = j0 - 2 + tx;       gc1 += (gc1 < 0) ? MG : 0;  gc1 -= (gc1 >= MG) ? MG : 0;
    const bool cok1 = (unsigned)(gc1 - 1) < (unsigned)HW;
    const int  xc1  = cok1 ? (gc1 - 1) : 0;
    int gc2 = j0 + 62 + tx;      gc2 -= (gc2 >= MG) ? MG : 0;   // col tx+64: j0-2+tx+64
    const bool cok2 = (unsigned)(gc2 - 1) < (unsigned)HW;
    const int  xc2  = cok2 ? (gc2 - 1) : 0;

    #pragma unroll
    for (int k = 0; k < 5; ++k) {
        const int r = ty + 4 * k;                 // 0..19
        int gr = i0 - 2 + r;  gr += (gr < 0) ? MG : 0;  gr -= (gr >= MG) ? MG : 0;
        const bool rok = (unsigned)(gr - 1) < (unsigned)HW;   // wave-uniform
        const float* rowp = xd + (size_t)(rok ? (gr - 1) : 0) * HW;
        xs[r][tx] = (rok && cok1) ? rowp[xc1] : 0.0f;
        if (tx < 4)
            xs[r][tx + 64] = (rok && cok2) ? rowp[xc2] : 0.0f;
    }
    __syncthreads();

    // ---- mag/cls: 18 rows x 66 cols ----
    #pragma unroll
    for (int k = 0; k < 5; ++k) {
        const int r = ty + 4 * k;
        if (r < 18) {
            #pragma unroll
            for (int h = 0; h < 2; ++h) {
                const int c = tx + 64 * h;
                if (h == 0 || tx < 2) {
                    float gx, gy;
                    {
                        #pragma clang fp contract(off)
                        float x00 = xs[r][c],   x01 = xs[r][c+1],   x02 = xs[r][c+2];
                        float x10 = xs[r+1][c],                     x12 = xs[r+1][c+2];
                        float x20 = xs[r+2][c], x21 = xs[r+2][c+1], x22 = xs[r+2][c+2];
                        { float A = -x00; float B = x02 + (-x20); float C = 2.0f*x12; float D = -2.0f*x10;
                          float E = A + B; float F = C + D; gx = (E + F) + x22; }
                        { float A = -x00; float B = (-x02) + x20; float C = -2.0f*x01; float D = 2.0f*x21;
                          float E = A + B; float F = C + D; gy = (E + F) + x22; }
                    }
                    float m;
                    {
                        #pragma clang fp contract(off)
                        float p = gx * gx;
                        float q = gy * gy;
                        m = sqrtf(p + q);
                    }
                    mag_s[r][c] = m;
                    cls_s[r][c] = (unsigned char)classify(gx, gy);
                }
            }
        }
    }
    __syncthreads();

    // ---- NMS 16x64 interior -> nms + per-thread max ----
    float* nd = nms + (size_t)d * MG * MG;
    float tmax = 0.0f;
    #pragma unroll
    for (int q = 0; q < 4; ++q) {
        const int ry = ty + 4 * q;
        const int gi = i0 + ry, gj = j0 + tx;
        if (gi < MG && gj < MG) {
            const int r = ry + 1, c = tx + 1;
            float m = mag_s[r][c]; int cl = cls_s[r][c]; float a, b;
            if (cl == 0)      { a = mag_s[r][c-1];   b = mag_s[r][c+1];   }
            else if (cl == 1) { a = mag_s[r-1][c-1]; b = mag_s[r+1][c+1]; }
            else if (cl == 2) { a = mag_s[r-1][c];   b = mag_s[r+1][c];   }
            else              { a = mag_s[r-1][c+1]; b = mag_s[r+1][c-1]; }
            float v = (m >= a && m >= b) ? m : 0.0f;
            nd[(size_t)gi * MG + gj] = v;
            tmax = fmaxf(tmax, v);
        }
    }

    for (int off = 32; off > 0; off >>= 1)
        tmax = fmaxf(tmax, __shfl_down(tmax, off, 64));
    __shared__ float wmax[4];
    const int t = ty * 64 + tx;
    if ((t & 63) == 0) wmax[t >> 6] = tmax;
    __syncthreads();
    if (t == 0) {
        float bm = fmaxf(fmaxf(wmax[0], wmax[1]), fmaxf(wmax[2], wmax[3]));
        atomicMax(smax + d, __float_as_uint(bm));  // nonneg: uint order-preserving
    }
}

// ---------- k2: thresholds + 3x3 strong-pool hysteresis + crop ----------
__global__ __launch_bounds__(256) void k_edges(const float* __restrict__ nms,
                                               const unsigned int* __restrict__ smax,
                                               float* __restrict__ out) {
    __shared__ float ns[18][67];
    const int tx = threadIdx.x, ty = threadIdx.y;
    const int d   = blockIdx.z;
    const int ys  = blockIdx.y * 16;
    const int xs0 = blockIdx.x * 64;
    const float* nd = nms + (size_t)d * MG * MG;

    // stage nms rows ys..ys+17, cols xs0..xs0+65 (all in-bounds: max 513)
    #pragma unroll
    for (int k = 0; k < 5; ++k) {
        const int r = ty + 4 * k;
        if (r < 18) {
            const float* rp = nd + (size_t)(ys + r) * MG + xs0;
            ns[r][tx] = rp[tx];
            if (tx < 2) ns[r][tx + 64] = rp[tx + 64];
        }
    }
    __syncthreads();

    const float high = __uint_as_float(smax[d]) * 0.05f;
    const float low  = high * 0.01f;

    float* od = out + (size_t)d * HW * HW;
    #pragma unroll
    for (int q = 0; q < 4; ++q) {
        const int ry = ty + 4 * q;
        const int y = ys + ry, xo = xs0 + tx;
        const int r = ry + 1,  c  = tx + 1;
        float m = ns[r][c];
        float e;
        if (m >= high) {
            e = 1.0f;
        } else if (m >= low) {
            bool pooled =
                ns[r-1][c-1] >= high || ns[r-1][c] >= high || ns[r-1][c+1] >= high ||
                ns[r][c-1]   >= high ||                       ns[r][c+1]   >= high ||
                ns[r+1][c-1] >= high || ns[r+1][c] >= high || ns[r+1][c+1] >= high;
            e = pooled ? 1.0f : 0.0f;
        } else {
            e = 0.0f;
        }
        od[(size_t)y * HW + xo] = e;
    }
}

extern "C" void kernel_launch(void* const* d_in, const int* in_sizes, int n_in,
                              void* d_out, int out_size, void* d_ws, size_t ws_size,
                              hipStream_t stream) {
    const float* x = (const float*)d_in[0];
    float* out = (float*)d_out;
    float* nms = (float*)d_ws;                                   // 514*514*128*4 = 135.26 MB
    unsigned int* smax = (unsigned int*)((char*)d_ws + (size_t)DD * MG * MG * sizeof(float));

    hipMemsetAsync(smax, 0, DD * sizeof(unsigned int), stream);

    dim3 blk(64, 4, 1);
    k_nms  <<<dim3(9, 33, DD), blk, 0, stream>>>(x, nms, smax);  // full 514 grid
    k_edges<<<dim3(8, 32, DD), blk, 0, stream>>>(nms, smax, out);
}

// Round 19
// 346.251 us; speedup vs baseline: 1.3049x; 1.1320x over previous
//
#include <hip/hip_runtime.h>
#include <math.h>

#define DD 128
#define HW 512
#define MG 514

// Verified reference stack (r10/r11/r14): G1 predux-tree colmajor conv,
// contract-off mul/add mag, fd-hybrid classifier.
// r19: de-bloat k_nms — magic-div flat maps (full lane utilization),
// branch-free NMS neighbor addressing, noinline rare-path atan2.

// ---- fdlibm/glibc float atan (bit-exact port) ----
static __device__ float fd_atanf(float x) {
    #pragma clang fp contract(off)
    const unsigned hx = __float_as_uint(x);
    const unsigned ix = hx & 0x7fffffffu;
    const double A0 = 0.46364760900080611621425623146121440203;
    const double A1 = 0.78539816339744830961566084581987572105;
    const double A2 = 0.98279372324732906798571061101466601449;
    const double A3 = 1.57079632679489661923132169163975144210;
    const float aT0 =  3.3333328366e-01f;
    const float aT1 = -1.9999158382e-01f;
    const float aT2 =  1.4253635705e-01f;
    const float aT3 = -1.0648017377e-01f;
    const float aT4 =  6.1687607318e-02f;
    float z, w, s1, s2;
    int id;
    double a;
    if (ix >= 0x4c800000u) {
        a = A3;
        float hi = (float)a; if ((double)hi > a) hi = __uint_as_float(__float_as_uint(hi) - 1u);
        float lo = (float)(a - (double)hi);
        float r = hi + lo;
        return (hx >> 31) ? -r : r;
    }
    if (ix < 0x3ee00000u) {
        if (ix < 0x39800000u) return x;
        id = -1;
    } else {
        x = fabsf(x);
        if (ix < 0x3f980000u) {
            if (ix < 0x3f300000u) { id = 0; x = (2.0f * x - 1.0f) / (2.0f + x); }
            else                  { id = 1; x = (x - 1.0f) / (x + 1.0f); }
        } else {
            if (ix < 0x401c0000u) { id = 2; x = (x - 1.5f) / (1.0f + 1.5f * x); }
            else                  { id = 3; x = -1.0f / x; }
        }
    }
    z = x * x;
    w = z * z;
    s1 = z * (aT0 + w * (aT2 + w * aT4));
    s2 = w * (aT1 + w * aT3);
    if (id < 0) return x - x * (s1 + s2);
    a = (id == 0) ? A0 : (id == 1) ? A1 : (id == 2) ? A2 : A3;
    float hi = (float)a; if ((double)hi > a) hi = __uint_as_float(__float_as_uint(hi) - 1u);
    float lo = (float)(a - (double)hi);
    z = hi - ((x * (s1 + s2) - lo) - x);
    return (hx >> 31) ? -z : z;
}

static __device__ __noinline__ int cls_fd(float y, float x) {
    #pragma clang fp contract(off)
    const unsigned hx = __float_as_uint(x), hy = __float_as_uint(y);
    const unsigned ix = hx & 0x7fffffffu, iy = hy & 0x7fffffffu;
    unsigned m = ((hy >> 31) & 1u) | ((hx >> 30) & 2u);
    const double PI_D = 3.14159265358979323846264338327950288420;
    const float pi_f  = (float)PI_D;
    const float pi_lo = (float)(PI_D - (double)pi_f);
    const float pi4_f = (float)(PI_D / 4.0);
    const float pi2_f = (float)(PI_D / 2.0);
    float v;
    if (iy == 0) {
        v = (m == 0 || m == 1) ? y : (m == 2 ? pi_f : -pi_f);
    } else if (ix == 0) {
        v = (m & 1u) ? -pi2_f : pi2_f;
    } else if (ix + (26u << 23) < iy) {
        v = (m & 1u) ? -pi2_f : pi2_f;
    } else {
        float z;
        if ((m & 2u) && iy + (26u << 23) < ix) z = 0.0f;
        else z = fd_atanf(fabsf(y / x));
        switch (m) {
            case 0:  v = z; break;
            case 1:  v = -z; break;
            case 2:  v = pi_f - (z - pi_lo); break;
            default: v = (z - pi_lo) - pi_f; break;
        }
    }
    float t = v / pi4_f;
    int n = (int)rintf(t);
    return n & 3;
}

static __device__ __forceinline__ int classify(float gx, float gy) {
    #pragma clang fp contract(off)
    float ax = fabsf(gx), ay = fabsf(gy);
    const float T = 0.41421356237309504880f;   // tan(pi/8)
    float r1 = ay - ax * T;
    float r2 = ax - ay * T;
    float eps = 1e-4f * (ax + ay);
    if (fabsf(r1) > eps && fabsf(r2) > eps) {
        if (r1 < 0.0f) return 0;
        if (r2 < 0.0f) return 2;
        return ((__float_as_uint(gx) ^ __float_as_uint(gy)) >> 31) ? 3 : 1;
    }
    return cls_fd(gy, gx);
}

// ---------- k1: stage x -> mag/cls -> NMS -> nms(ws) + per-slice max ----------
__global__ __launch_bounds__(256) void k_nms(const float* __restrict__ x,
                                             float* __restrict__ nms,
                                             unsigned int* __restrict__ smax) {
    __shared__ float         xs[20][69];
    __shared__ float         mag_s[18][67];
    __shared__ unsigned char cls_s[18][67];
    const int tx = threadIdx.x, ty = threadIdx.y;
    const int t  = ty * 64 + tx;
    const int d  = blockIdx.z;
    const int i0 = blockIdx.y * 16;
    const int j0 = blockIdx.x * 64;
    const float* xd = x + (size_t)d * HW * HW;

    // ---- stage x: 20 rows x 68 cols (rows i0-2.., cols j0-2.., wrap + zero ring)
    #pragma unroll
    for (int k = 0; k < 6; ++k) {
        const int idx = t + 256 * k;
        if (idx < 20 * 68) {
            const int r = (idx * 964) >> 16;          // idx / 68 (exact for idx<1360)
            const int c = idx - 68 * r;
            int gr = i0 - 2 + r;  gr += (gr < 0) ? MG : 0;  gr -= (gr >= MG) ? MG : 0;
            int gc = j0 - 2 + c;  gc += (gc < 0) ? MG : 0;  gc -= (gc >= MG) ? MG : 0;
            float v = 0.0f;
            if (((unsigned)(gr - 1) < (unsigned)HW) & ((unsigned)(gc - 1) < (unsigned)HW))
                v = xd[(size_t)(gr - 1) * HW + (gc - 1)];
            xs[r][c] = v;
        }
    }
    __syncthreads();

    // ---- mag/cls: 18 rows x 66 cols ----
    #pragma unroll
    for (int k = 0; k < 5; ++k) {
        const int idx = t + 256 * k;
        if (idx < 18 * 66) {
            const int r = (idx * 993) >> 16;          // idx / 66 (exact for idx<1188)
            const int c = idx - 66 * r;
            float gx, gy;
            {
                #pragma clang fp contract(off)
                float x00 = xs[r][c],   x01 = xs[r][c+1],   x02 = xs[r][c+2];
                float x10 = xs[r+1][c],                     x12 = xs[r+1][c+2];
                float x20 = xs[r+2][c], x21 = xs[r+2][c+1], x22 = xs[r+2][c+2];
                { float A = -x00; float B = x02 + (-x20); float C = 2.0f*x12; float D = -2.0f*x10;
                  float E = A + B; float F = C + D; gx = (E + F) + x22; }
                { float A = -x00; float B = (-x02) + x20; float C = -2.0f*x01; float D = 2.0f*x21;
                  float E = A + B; float F = C + D; gy = (E + F) + x22; }
            }
            float m;
            {
                #pragma clang fp contract(off)
                float p = gx * gx;
                float q = gy * gy;
                m = sqrtf(p + q);
            }
            mag_s[r][c] = m;
            cls_s[r][c] = (unsigned char)classify(gx, gy);
        }
    }
    __syncthreads();

    // ---- NMS 16x64 interior -> nms + per-thread max (branch-free neighbors) ----
    float* nd = nms + (size_t)d * MG * MG;
    float tmax = 0.0f;
    #pragma unroll
    for (int q = 0; q < 4; ++q) {
        const int ry = ty + 4 * q;
        const int gi = i0 + ry, gj = j0 + tx;
        if ((gi < MG) & (gj < MG)) {
            const int r = ry + 1, c = tx + 1;
            float m = mag_s[r][c];
            int cl = cls_s[r][c];
            // offsets: cl0:(0,-1) cl1:(-1,-1) cl2:(-1,0) cl3:(-1,+1); b = -a
            int adr = (cl == 0) ? 0 : -1;
            int adc = (cl == 3) ? 1 : ((cl == 2) ? 0 : -1);
            float a = mag_s[r + adr][c + adc];
            float b = mag_s[r - adr][c - adc];
            float v = (m >= a && m >= b) ? m : 0.0f;
            nd[(size_t)gi * MG + gj] = v;
            tmax = fmaxf(tmax, v);
        }
    }

    for (int off = 32; off > 0; off >>= 1)
        tmax = fmaxf(tmax, __shfl_down(tmax, off, 64));
    __shared__ float wmax[4];
    if ((t & 63) == 0) wmax[t >> 6] = tmax;
    __syncthreads();
    if (t == 0) {
        float bm = fmaxf(fmaxf(wmax[0], wmax[1]), fmaxf(wmax[2], wmax[3]));
        atomicMax(smax + d, __float_as_uint(bm));  // nonneg: uint order-preserving
    }
}

// ---------- k2: thresholds + 3x3 strong-pool hysteresis + crop ----------
__global__ __launch_bounds__(256) void k_edges(const float* __restrict__ nms,
                                               const unsigned int* __restrict__ smax,
                                               float* __restrict__ out) {
    __shared__ float ns[18][67];
    const int tx = threadIdx.x, ty = threadIdx.y;
    const int d   = blockIdx.z;
    const int ys  = blockIdx.y * 16;
    const int xs0 = blockIdx.x * 64;
    const float* nd = nms + (size_t)d * MG * MG;

    #pragma unroll
    for (int k = 0; k < 5; ++k) {
        const int r = ty + 4 * k;
        if (r < 18) {
            const float* rp = nd + (size_t)(ys + r) * MG + xs0;
            ns[r][tx] = rp[tx];
            if (tx < 2) ns[r][tx + 64] = rp[tx + 64];
        }
    }
    __syncthreads();

    const float high = __uint_as_float(smax[d]) * 0.05f;
    const float low  = high * 0.01f;

    float* od = out + (size_t)d * HW * HW;
    #pragma unroll
    for (int q = 0; q < 4; ++q) {
        const int ry = ty + 4 * q;
        const int y = ys + ry, xo = xs0 + tx;
        const int r = ry + 1,  c  = tx + 1;
        float m = ns[r][c];
        float e;
        if (m >= high) {
            e = 1.0f;
        } else if (m >= low) {
            bool pooled =
                ns[r-1][c-1] >= high || ns[r-1][c] >= high || ns[r-1][c+1] >= high ||
                ns[r][c-1]   >= high ||                       ns[r][c+1]   >= high ||
                ns[r+1][c-1] >= high || ns[r+1][c] >= high || ns[r+1][c+1] >= high;
            e = pooled ? 1.0f : 0.0f;
        } else {
            e = 0.0f;
        }
        od[(size_t)y * HW + xo] = e;
    }
}

extern "C" void kernel_launch(void* const* d_in, const int* in_sizes, int n_in,
                              void* d_out, int out_size, void* d_ws, size_t ws_size,
                              hipStream_t stream) {
    const float* x = (const float*)d_in[0];
    float* out = (float*)d_out;
    float* nms = (float*)d_ws;                                   // 514*514*128*4 = 135.26 MB
    unsigned int* smax = (unsigned int*)((char*)d_ws + (size_t)DD * MG * MG * sizeof(float));

    hipMemsetAsync(smax, 0, DD * sizeof(unsigned int), stream);

    dim3 blk(64, 4, 1);
    k_nms  <<<dim3(9, 33, DD), blk, 0, stream>>>(x, nms, smax);  // full 514 grid
    k_edges<<<dim3(8, 32, DD), blk, 0, stream>>>(nms, smax, out);
}